// Round 1
// 992.146 us; speedup vs baseline: 1.4606x; 1.4606x over previous
//
#include <hip/hip_runtime.h>

typedef unsigned char u8;
typedef unsigned int u32;
using f32x4 = __attribute__((ext_vector_type(4))) float;

#define E4M3_AMAX 216.0f
#define FP8_MAXV 240.0f

#define BM 128
#define BN 128
#define BK 64   // fp8 bytes along K per tile

#define GLD_LDS16(g, l) \
    __builtin_amdgcn_global_load_lds((const __attribute__((address_space(1))) void*)(g), \
                                     (__attribute__((address_space(3))) void*)(l), 16, 0, 0)

// ---------------- abs-max reduction (exact: uint compare on |f32| bits) ------
__global__ void maxabs_kernel(const float* __restrict__ x, long n4, u32* __restrict__ out) {
    long stride = (long)gridDim.x * blockDim.x;
    long i = (long)blockIdx.x * blockDim.x + threadIdx.x;
    u32 m = 0;
    const float4* x4 = (const float4*)x;
    for (long j = i; j < n4; j += stride) {
        float4 v = x4[j];
        u32 a = __float_as_uint(fabsf(v.x));
        u32 b = __float_as_uint(fabsf(v.y));
        u32 c = __float_as_uint(fabsf(v.z));
        u32 d = __float_as_uint(fabsf(v.w));
        m = a > m ? a : m;
        m = b > m ? b : m;
        m = c > m ? c : m;
        m = d > m ? d : m;
    }
    #pragma unroll
    for (int off = 32; off > 0; off >>= 1) {
        u32 o = (u32)__shfl_down((unsigned int)m, (unsigned int)off, 64);
        m = o > m ? o : m;
    }
    __shared__ u32 sm[8];
    int wave = threadIdx.x >> 6, lane = threadIdx.x & 63;
    if (lane == 0) sm[wave] = m;
    __syncthreads();
    if (threadIdx.x == 0) {
        u32 r = sm[0];
        int nw = blockDim.x >> 6;
        for (int w = 1; w < nw; ++w) r = sm[w] > r ? sm[w] : r;
        atomicMax(out, r);
    }
}

// ---------------- quantize f32 -> e4m3fn bytes (HW RNE cvt) ------------------
__global__ void quant_kernel(const float* __restrict__ x, u8* __restrict__ y, long n4,
                             const u32* __restrict__ maxbits, int idx) {
    float mx = __uint_as_float(maxbits[idx]);
    float scale = E4M3_AMAX / mx;
    long stride = (long)gridDim.x * blockDim.x;
    long i = (long)blockIdx.x * blockDim.x + threadIdx.x;
    const float4* x4 = (const float4*)x;
    int* y4 = (int*)y;
    for (long j = i; j < n4; j += stride) {
        float4 v = x4[j];
        float a = fminf(fmaxf(v.x * scale, -FP8_MAXV), FP8_MAXV);
        float b = fminf(fmaxf(v.y * scale, -FP8_MAXV), FP8_MAXV);
        float c = fminf(fmaxf(v.z * scale, -FP8_MAXV), FP8_MAXV);
        float d = fminf(fmaxf(v.w * scale, -FP8_MAXV), FP8_MAXV);
        int p = 0;
        p = __builtin_amdgcn_cvt_pk_fp8_f32(a, b, p, false);  // bytes 0,1
        p = __builtin_amdgcn_cvt_pk_fp8_f32(c, d, p, true);   // bytes 2,3
        y4[j] = p;
    }
}

// ---------------- fp8 GEMM: C[m,n] = sum_k A8[m,k]*W8[n,k], dequant + bias ---
// 128x128 block tile, 256 threads (4 waves), 64x64 per wave (4x4 of 16x16x32).
//
// LDS bank-conflict fix (this revision): 16B-block XOR swizzle, same involution
// on the staging SOURCE (global col) and the fragment READ address:
//     colblock16(row) ^= (row>>1) & 3
// LDS destination stays linear (global_load_lds requirement). After the XOR,
// each wave64 ds_read_b64 hits every bank exactly 4x (= the 512B minimum);
// before, all 64 lanes hit 8 even banks (16 accesses/bank, 4x slowdown).
__global__ __launch_bounds__(256) void gemm_fp8_kernel(
    const u8* __restrict__ A,   // [M,K] fp8
    const u8* __restrict__ B,   // [N,K] fp8 (weight, K-contiguous = B^T form)
    const float* __restrict__ bias,
    const u32* __restrict__ scales,
    float* __restrict__ C, int M, int N, int K)
{
    __shared__ u8 As[BM * BK];   // row-major [128][64], 16B blocks swizzled per row
    __shared__ u8 Bs[BN * BK];

    const int tid = threadIdx.x;
    const int wave = tid >> 6;
    const int lane = tid & 63;
    const int fr = lane & 15;      // frag row (A) / col (B/D)
    const int quad = lane >> 4;    // 0..3

    const int bm = blockIdx.y * BM;
    const int bn = blockIdx.x * BN;
    const int wm = (wave >> 1) * 64;
    const int wn = (wave & 1) * 64;

    f32x4 acc[4][4] = {};

    // staging: each wave fills 2 chunks of 1024B per tile (chunk c = rows 16c..16c+15)
    // lane i of chunk writes LDS [chunk*1024 + i*16] (LINEAR dest);
    // source row = 16*wave + i/4; source 16B-col = (i&3) ^ ((row>>1)&3)  [inverse swizzle]
    const int srow = 16 * wave + (lane >> 2);
    const int swzs = (lane >> 3) & 3;                 // == (srow>>1)&3 ; also for srow+64
    const int scol = ((lane & 3) ^ swzs) * 16;
    const u8* gA = A + (size_t)(bm + srow) * K + scol;
    const u8* gB = B + (size_t)(bn + srow) * K + scol;
    u8* lA = As + wave * 1024;     // wave-uniform LDS base
    u8* lB = Bs + wave * 1024;

    // read-side swizzle: row = wm + i*16 + fr, (row>>1)&3 == (fr>>1)&3 for all i,wm
    const int swzr = (fr >> 1) & 3;

    for (int k0 = 0; k0 < K; k0 += BK) {
        GLD_LDS16(gA,              lA);
        GLD_LDS16(gA + (size_t)64 * K, lA + 4096);   // rows +64
        GLD_LDS16(gB,              lB);
        GLD_LDS16(gB + (size_t)64 * K, lB + 4096);
        gA += BK;
        gB += BK;
        __syncthreads();

        #pragma unroll
        for (int ks = 0; ks < 2; ++ks) {
            const int colx = (ks * 32 + quad * 8) ^ (swzr << 4);  // swizzled col bytes
            long a[4], b[4];
            #pragma unroll
            for (int i = 0; i < 4; ++i) {
                a[i] = *(const long*)(As + (wm + i * 16 + fr) * BK + colx);
                b[i] = *(const long*)(Bs + (wn + i * 16 + fr) * BK + colx);
            }
            #pragma unroll
            for (int i = 0; i < 4; ++i)
                #pragma unroll
                for (int j = 0; j < 4; ++j)
                    acc[i][j] = __builtin_amdgcn_mfma_f32_16x16x32_fp8_fp8(a[i], b[j], acc[i][j], 0, 0, 0);
        }
        __syncthreads();
    }

    // dequant epilogue: out = acc * (1/i_scale) * (1/w_scale) + bias
    const float mi = __uint_as_float(scales[0]);
    const float mw = __uint_as_float(scales[1]);
    const float i_scale = E4M3_AMAX / mi;
    const float w_scale = E4M3_AMAX / mw;
    const float deq = (1.0f / i_scale) * (1.0f / w_scale);

    #pragma unroll
    for (int i = 0; i < 4; ++i) {
        const int row0 = bm + wm + i * 16 + quad * 4;
        #pragma unroll
        for (int j = 0; j < 4; ++j) {
            const int col = bn + wn + j * 16 + fr;
            const float bv = bias[col];
            #pragma unroll
            for (int rg = 0; rg < 4; ++rg) {
                C[(size_t)(row0 + rg) * N + col] = acc[i][j][rg] * deq + bv;
            }
        }
    }
}

extern "C" void kernel_launch(void* const* d_in, const int* in_sizes, int n_in,
                              void* d_out, int out_size, void* d_ws, size_t ws_size,
                              hipStream_t stream) {
    const float* inp    = (const float*)d_in[0];
    const float* weight = (const float*)d_in[1];
    const float* bias   = (const float*)d_in[2];
    float* out = (float*)d_out;

    const int N = in_sizes[2];                        // 4096
    const int K = in_sizes[1] / N;                    // 4096
    const long icount = in_sizes[0];                  // 67108864
    const int M = (int)(icount / K);                  // 16384
    const long wcount = (long)N * K;

    u32* scales = (u32*)d_ws;
    u8* x8 = (u8*)d_ws + 256;
    u8* w8 = x8 + (size_t)M * K;

    // zero the amax accumulators (ws is poisoned 0xAA before each call)
    hipMemsetAsync(d_ws, 0, 16, stream);

    maxabs_kernel<<<2048, 256, 0, stream>>>(inp, icount / 4, scales + 0);
    maxabs_kernel<<<1024, 256, 0, stream>>>(weight, wcount / 4, scales + 1);

    quant_kernel<<<4096, 256, 0, stream>>>(inp, x8, icount / 4, scales, 0);
    quant_kernel<<<2048, 256, 0, stream>>>(weight, w8, wcount / 4, scales, 1);

    dim3 grid(N / BN, M / BM);
    gemm_fp8_kernel<<<grid, 256, 0, stream>>>(x8, w8, bias, scales, out, M, N, K);
}

// Round 2
// 887.211 us; speedup vs baseline: 1.6333x; 1.1183x over previous
//
#include <hip/hip_runtime.h>

typedef unsigned char u8;
typedef unsigned int u32;
using f32x4 = __attribute__((ext_vector_type(4))) float;

#define E4M3_AMAX 216.0f
#define FP8_MAXV 240.0f

#define BM 128
#define BN 128
#define BK 64   // fp8 bytes along K per tile

#define GLD_LDS16(g, l) \
    __builtin_amdgcn_global_load_lds((const __attribute__((address_space(1))) void*)(g), \
                                     (__attribute__((address_space(3))) void*)(l), 16, 0, 0)

// ---------------- fused abs-max reduction (exact: uint compare on |f32| bits)
// blocks [0, blocksA) reduce tensor a -> outa; the rest reduce b -> outb.
__global__ void maxabs2_kernel(const float* __restrict__ a, long na4, u32* __restrict__ outa,
                               const float* __restrict__ b, long nb4, u32* __restrict__ outb,
                               int blocksA) {
    const float4* x4;
    long n4;
    u32* out;
    long bid, nb;
    if ((int)blockIdx.x < blocksA) {
        x4 = (const float4*)a; n4 = na4; out = outa; bid = blockIdx.x; nb = blocksA;
    } else {
        x4 = (const float4*)b; n4 = nb4; out = outb; bid = blockIdx.x - blocksA; nb = gridDim.x - blocksA;
    }
    long stride = nb * blockDim.x;
    long i = bid * blockDim.x + threadIdx.x;
    u32 m = 0;
    for (long j = i; j < n4; j += stride) {
        float4 v = x4[j];
        u32 pa = __float_as_uint(fabsf(v.x));
        u32 pb = __float_as_uint(fabsf(v.y));
        u32 pc = __float_as_uint(fabsf(v.z));
        u32 pd = __float_as_uint(fabsf(v.w));
        m = pa > m ? pa : m;
        m = pb > m ? pb : m;
        m = pc > m ? pc : m;
        m = pd > m ? pd : m;
    }
    #pragma unroll
    for (int off = 32; off > 0; off >>= 1) {
        u32 o = (u32)__shfl_down((unsigned int)m, (unsigned int)off, 64);
        m = o > m ? o : m;
    }
    __shared__ u32 sm[8];
    int wave = threadIdx.x >> 6, lane = threadIdx.x & 63;
    if (lane == 0) sm[wave] = m;
    __syncthreads();
    if (threadIdx.x == 0) {
        u32 r = sm[0];
        int nw = blockDim.x >> 6;
        for (int w = 1; w < nw; ++w) r = sm[w] > r ? sm[w] : r;
        atomicMax(out, r);
    }
}

// ---------------- fused quantize f32 -> e4m3fn bytes (HW RNE cvt) ------------
// 64B loads (4x float4), 16B int4 stores. blocks [0, blocksA) do tensor a.
__global__ void quant2_kernel(const float* __restrict__ a, u8* __restrict__ ya, long na16,
                              const float* __restrict__ b, u8* __restrict__ yb, long nb16,
                              const u32* __restrict__ maxbits, int blocksA) {
    const float4* x4;
    int4* y4;
    long n16, bid, nb;
    float mx;
    if ((int)blockIdx.x < blocksA) {
        x4 = (const float4*)a; y4 = (int4*)ya; n16 = na16; bid = blockIdx.x; nb = blocksA;
        mx = __uint_as_float(maxbits[0]);
    } else {
        x4 = (const float4*)b; y4 = (int4*)yb; n16 = nb16; bid = blockIdx.x - blocksA; nb = gridDim.x - blocksA;
        mx = __uint_as_float(maxbits[1]);
    }
    float scale = E4M3_AMAX / mx;
    long stride = nb * blockDim.x;
    long i = bid * blockDim.x + threadIdx.x;
    for (long j = i; j < n16; j += stride) {
        int4 p4;
        #pragma unroll
        for (int q = 0; q < 4; ++q) {
            float4 v = x4[j * 4 + q];
            float pa = fminf(fmaxf(v.x * scale, -FP8_MAXV), FP8_MAXV);
            float pb = fminf(fmaxf(v.y * scale, -FP8_MAXV), FP8_MAXV);
            float pc = fminf(fmaxf(v.z * scale, -FP8_MAXV), FP8_MAXV);
            float pd = fminf(fmaxf(v.w * scale, -FP8_MAXV), FP8_MAXV);
            int p = 0;
            p = __builtin_amdgcn_cvt_pk_fp8_f32(pa, pb, p, false);  // bytes 0,1
            p = __builtin_amdgcn_cvt_pk_fp8_f32(pc, pd, p, true);   // bytes 2,3
            ((int*)&p4)[q] = p;
        }
        y4[j] = p4;
    }
}

// ---------------- fp8 GEMM: C[m,n] = sum_k A8[m,k]*W8[n,k], dequant + bias ---
// 128x128 block tile, 256 threads (4 waves), 64x64 per wave (4x4 of 16x16x32).
//
// LDS 16B-block XOR swizzle (round 1, kept): same involution on staging SOURCE
// (global col) and fragment READ address: colblock16 ^= (row>>1)&3. LDS dest
// stays linear (global_load_lds requirement). ds_read_b64 hits every bank 4x.
//
// This revision:
//  - T1 XCD-chunked blockIdx swizzle (nwg=4096 % 8 == 0 -> simple bijective).
//  - Double-buffered LDS prefetch (minimum 2-phase): per tile,
//    barrier -> issue STAGE(next tile -> other buf) -> ds_read+MFMA(cur buf).
//    The implicit vmcnt(0)+lgkmcnt(0) drain the compiler emits before the NEXT
//    s_barrier is exactly the wait the prefetched loads need -> load latency
//    hides under one full compute phase instead of being serially exposed.
__device__ __forceinline__ void stage_tile(const u8* gA, const u8* gB, u8* lA, u8* lB, int K) {
    GLD_LDS16(gA,                  lA);
    GLD_LDS16(gA + (size_t)64 * K, lA + 4096);   // rows +64
    GLD_LDS16(gB,                  lB);
    GLD_LDS16(gB + (size_t)64 * K, lB + 4096);
}

__device__ __forceinline__ void compute_tile(const u8* Asb, const u8* Bsb, f32x4 acc[4][4],
                                             int wm, int wn, int fr, int quad, int swzr) {
    #pragma unroll
    for (int ks = 0; ks < 2; ++ks) {
        const int colx = (ks * 32 + quad * 8) ^ (swzr << 4);  // swizzled col bytes
        long a[4], b[4];
        #pragma unroll
        for (int i = 0; i < 4; ++i) {
            a[i] = *(const long*)(Asb + (wm + i * 16 + fr) * BK + colx);
            b[i] = *(const long*)(Bsb + (wn + i * 16 + fr) * BK + colx);
        }
        #pragma unroll
        for (int i = 0; i < 4; ++i)
            #pragma unroll
            for (int j = 0; j < 4; ++j)
                acc[i][j] = __builtin_amdgcn_mfma_f32_16x16x32_fp8_fp8(a[i], b[j], acc[i][j], 0, 0, 0);
    }
}

__global__ __launch_bounds__(256) void gemm_fp8_kernel(
    const u8* __restrict__ A,   // [M,K] fp8
    const u8* __restrict__ B,   // [N,K] fp8 (weight, K-contiguous = B^T form)
    const float* __restrict__ bias,
    const u32* __restrict__ scales,
    float* __restrict__ C, int M, int N, int K)
{
    // double-buffered: per buffer As (8KB) + Bs (8KB); total 32KB
    __shared__ u8 smem[2][2 * BM * BK];

    const int tid = threadIdx.x;
    const int wave = tid >> 6;
    const int lane = tid & 63;
    const int fr = lane & 15;      // frag row (A) / col (B/D)
    const int quad = lane >> 4;    // 0..3

    // T1: XCD-aware chunked swizzle of the linear block id (bijective: nwg%8==0)
    const int nwg = (int)(gridDim.x * gridDim.y);
    int orig = (int)(blockIdx.y * gridDim.x + blockIdx.x);
    int swz = orig;
    if ((nwg & 7) == 0) {
        const int cpx = nwg >> 3;
        swz = (orig & 7) * cpx + (orig >> 3);
    }
    const int bm = (swz / (int)gridDim.x) * BM;
    const int bn = (swz % (int)gridDim.x) * BN;

    const int wm = (wave >> 1) * 64;
    const int wn = (wave & 1) * 64;

    f32x4 acc[4][4] = {};

    // staging: each wave fills 2 chunks of 1024B per matrix per tile
    // lane i writes LDS [chunk*1024 + i*16] (LINEAR dest);
    // source row = 16*wave + i/4; source 16B-col = (i&3) ^ ((row>>1)&3)
    const int srow = 16 * wave + (lane >> 2);
    const int swzs = (lane >> 3) & 3;                 // == (srow>>1)&3 ; also for srow+64
    const int scol = ((lane & 3) ^ swzs) * 16;
    const u8* gA = A + (size_t)(bm + srow) * K + scol;
    const u8* gB = B + (size_t)(bn + srow) * K + scol;
    const int lofs = wave * 1024;                     // wave-uniform LDS base offset

    u8* As0 = smem[0];            u8* Bs0 = smem[0] + BM * BK;
    u8* As1 = smem[1];            u8* Bs1 = smem[1] + BM * BK;

    // read-side swizzle: row = wm + i*16 + fr, (row>>1)&3 == (fr>>1)&3 for all i,wm
    const int swzr = (fr >> 1) & 3;

    // prologue: stage tile 0 into buffer 0
    stage_tile(gA, gB, As0 + lofs, Bs0 + lofs, K);

    for (int k0 = 0; k0 < K; k0 += 2 * BK) {
        // ---- tile k0 in buf0 ----
        __syncthreads();                              // drains buf0's loads (implicit vmcnt(0))
        if (k0 + BK < K)
            stage_tile(gA + (k0 + BK), gB + (k0 + BK), As1 + lofs, Bs1 + lofs, K);
        compute_tile(As0, Bs0, acc, wm, wn, fr, quad, swzr);

        // ---- tile k0+BK in buf1 ----
        __syncthreads();                              // drains buf1's loads
        if (k0 + 2 * BK < K)
            stage_tile(gA + (k0 + 2 * BK), gB + (k0 + 2 * BK), As0 + lofs, Bs0 + lofs, K);
        compute_tile(As1, Bs1, acc, wm, wn, fr, quad, swzr);
    }

    // dequant epilogue: out = acc * (1/i_scale) * (1/w_scale) + bias
    const float mi = __uint_as_float(scales[0]);
    const float mw = __uint_as_float(scales[1]);
    const float i_scale = E4M3_AMAX / mi;
    const float w_scale = E4M3_AMAX / mw;
    const float deq = (1.0f / i_scale) * (1.0f / w_scale);

    #pragma unroll
    for (int i = 0; i < 4; ++i) {
        const int row0 = bm + wm + i * 16 + quad * 4;
        #pragma unroll
        for (int j = 0; j < 4; ++j) {
            const int col = bn + wn + j * 16 + fr;
            const float bv = bias[col];
            #pragma unroll
            for (int rg = 0; rg < 4; ++rg) {
                C[(size_t)(row0 + rg) * N + col] = acc[i][j][rg] * deq + bv;
            }
        }
    }
}

extern "C" void kernel_launch(void* const* d_in, const int* in_sizes, int n_in,
                              void* d_out, int out_size, void* d_ws, size_t ws_size,
                              hipStream_t stream) {
    const float* inp    = (const float*)d_in[0];
    const float* weight = (const float*)d_in[1];
    const float* bias   = (const float*)d_in[2];
    float* out = (float*)d_out;

    const int N = in_sizes[2];                        // 4096
    const int K = in_sizes[1] / N;                    // 4096
    const long icount = in_sizes[0];                  // 67108864
    const int M = (int)(icount / K);                  // 16384
    const long wcount = (long)N * K;

    u32* scales = (u32*)d_ws;
    u8* x8 = (u8*)d_ws + 256;
    u8* w8 = x8 + (size_t)M * K;

    // zero the amax accumulators (ws is poisoned 0xAA before each call)
    hipMemsetAsync(d_ws, 0, 16, stream);

    // fused abs-max: blocks [0,2048) -> inp, [2048,2560) -> weight
    maxabs2_kernel<<<2560, 256, 0, stream>>>(inp, icount / 4, scales + 0,
                                             weight, wcount / 4, scales + 1, 2048);
    // fused quantize: 64B loads / 16B stores
    quant2_kernel<<<2560, 256, 0, stream>>>(inp, x8, icount / 16,
                                            weight, w8, wcount / 16, scales, 2048);

    dim3 grid(N / BN, M / BM);
    gemm_fp8_kernel<<<grid, 256, 0, stream>>>(x8, w8, bias, scales, out, M, N, K);
}

// Round 3
// 879.264 us; speedup vs baseline: 1.6481x; 1.0090x over previous
//
#include <hip/hip_runtime.h>

typedef unsigned char u8;
typedef unsigned int u32;
using f32x4 = __attribute__((ext_vector_type(4))) float;

#define E4M3_AMAX 216.0f
#define FP8_MAXV 240.0f

#define BM 128
#define BN 128
#define BK 64   // fp8 bytes along K per tile

#define GLD_LDS16(g, l) \
    __builtin_amdgcn_global_load_lds((const __attribute__((address_space(1))) void*)(g), \
                                     (__attribute__((address_space(3))) void*)(l), 16, 0, 0)

// ---------------- fused abs-max reduction (exact: uint compare on |f32| bits)
// blocks [0, blocksA) reduce tensor a -> outa; the rest reduce b -> outb.
__global__ void maxabs2_kernel(const float* __restrict__ a, long na4, u32* __restrict__ outa,
                               const float* __restrict__ b, long nb4, u32* __restrict__ outb,
                               int blocksA) {
    const float4* x4;
    long n4;
    u32* out;
    long bid, nb;
    if ((int)blockIdx.x < blocksA) {
        x4 = (const float4*)a; n4 = na4; out = outa; bid = blockIdx.x; nb = blocksA;
    } else {
        x4 = (const float4*)b; n4 = nb4; out = outb; bid = blockIdx.x - blocksA; nb = gridDim.x - blocksA;
    }
    long stride = nb * blockDim.x;
    long i = bid * blockDim.x + threadIdx.x;
    u32 m = 0;
    for (long j = i; j < n4; j += stride) {
        float4 v = x4[j];
        u32 pa = __float_as_uint(fabsf(v.x));
        u32 pb = __float_as_uint(fabsf(v.y));
        u32 pc = __float_as_uint(fabsf(v.z));
        u32 pd = __float_as_uint(fabsf(v.w));
        m = pa > m ? pa : m;
        m = pb > m ? pb : m;
        m = pc > m ? pc : m;
        m = pd > m ? pd : m;
    }
    #pragma unroll
    for (int off = 32; off > 0; off >>= 1) {
        u32 o = (u32)__shfl_down((unsigned int)m, (unsigned int)off, 64);
        m = o > m ? o : m;
    }
    __shared__ u32 sm[8];
    int wave = threadIdx.x >> 6, lane = threadIdx.x & 63;
    if (lane == 0) sm[wave] = m;
    __syncthreads();
    if (threadIdx.x == 0) {
        u32 r = sm[0];
        int nw = blockDim.x >> 6;
        for (int w = 1; w < nw; ++w) r = sm[w] > r ? sm[w] : r;
        atomicMax(out, r);
    }
}

// ---------------- fused quantize f32 -> e4m3fn bytes (HW RNE cvt) ------------
// Coalesced: each thread one float4 load (16B) -> one int store (4B).
// blocks [0, blocksA) do tensor a, the rest tensor b.
__global__ void quant2_kernel(const float* __restrict__ a, u8* __restrict__ ya, long na4,
                              const float* __restrict__ b, u8* __restrict__ yb, long nb4,
                              const u32* __restrict__ maxbits, int blocksA) {
    const float4* x4;
    int* y4;
    long n4, bid, nb;
    float mx;
    if ((int)blockIdx.x < blocksA) {
        x4 = (const float4*)a; y4 = (int*)ya; n4 = na4; bid = blockIdx.x; nb = blocksA;
        mx = __uint_as_float(maxbits[0]);
    } else {
        x4 = (const float4*)b; y4 = (int*)yb; n4 = nb4; bid = blockIdx.x - blocksA; nb = gridDim.x - blocksA;
        mx = __uint_as_float(maxbits[1]);
    }
    float scale = E4M3_AMAX / mx;
    long stride = nb * blockDim.x;
    long i = bid * blockDim.x + threadIdx.x;
    for (long j = i; j < n4; j += stride) {
        float4 v = x4[j];
        float pa = fminf(fmaxf(v.x * scale, -FP8_MAXV), FP8_MAXV);
        float pb = fminf(fmaxf(v.y * scale, -FP8_MAXV), FP8_MAXV);
        float pc = fminf(fmaxf(v.z * scale, -FP8_MAXV), FP8_MAXV);
        float pd = fminf(fmaxf(v.w * scale, -FP8_MAXV), FP8_MAXV);
        int p = 0;
        p = __builtin_amdgcn_cvt_pk_fp8_f32(pa, pb, p, false);  // bytes 0,1
        p = __builtin_amdgcn_cvt_pk_fp8_f32(pc, pd, p, true);   // bytes 2,3
        y4[j] = p;
    }
}

// ---------------- fp8 GEMM: C[m,n] = sum_k A8[m,k]*W8[n,k], dequant + bias ---
// 128x128 block tile, 256 threads (4 waves), 64x64 per wave (4x4 of 16x16x32).
//
// LDS 16B-block XOR swizzle (round 1, kept): same involution on staging SOURCE
// (global col) and fragment READ address: colblock16 ^= (row>>1)&3. LDS dest
// stays linear (global_load_lds requirement). ds_read_b64 hits every bank 4x.
//
// Double-buffered LDS prefetch (round 2, kept): per tile,
// barrier -> issue STAGE(next tile -> other buf) -> ds_read+MFMA(cur buf).
//
// Round 3: NO blockIdx swizzle. With gridDim.x=32 and round-robin dispatch,
// the natural mapping gives XCD = blockIdx.x % 8: each XCD owns 4 N-columns
// permanently, so its 2MB B-panel stays L2-resident while A streams via L3.
// The round-2 chunked swizzle broke this (FETCH 347MB -> 1031MB); reverted.
__device__ __forceinline__ void stage_tile(const u8* gA, const u8* gB, u8* lA, u8* lB, int K) {
    GLD_LDS16(gA,                  lA);
    GLD_LDS16(gA + (size_t)64 * K, lA + 4096);   // rows +64
    GLD_LDS16(gB,                  lB);
    GLD_LDS16(gB + (size_t)64 * K, lB + 4096);
}

__device__ __forceinline__ void compute_tile(const u8* Asb, const u8* Bsb, f32x4 acc[4][4],
                                             int wm, int wn, int fr, int quad, int swzr) {
    #pragma unroll
    for (int ks = 0; ks < 2; ++ks) {
        const int colx = (ks * 32 + quad * 8) ^ (swzr << 4);  // swizzled col bytes
        long a[4], b[4];
        #pragma unroll
        for (int i = 0; i < 4; ++i) {
            a[i] = *(const long*)(Asb + (wm + i * 16 + fr) * BK + colx);
            b[i] = *(const long*)(Bsb + (wn + i * 16 + fr) * BK + colx);
        }
        #pragma unroll
        for (int i = 0; i < 4; ++i)
            #pragma unroll
            for (int j = 0; j < 4; ++j)
                acc[i][j] = __builtin_amdgcn_mfma_f32_16x16x32_fp8_fp8(a[i], b[j], acc[i][j], 0, 0, 0);
    }
}

__global__ __launch_bounds__(256) void gemm_fp8_kernel(
    const u8* __restrict__ A,   // [M,K] fp8
    const u8* __restrict__ B,   // [N,K] fp8 (weight, K-contiguous = B^T form)
    const float* __restrict__ bias,
    const u32* __restrict__ scales,
    float* __restrict__ C, int M, int N, int K)
{
    // double-buffered: per buffer As (8KB) + Bs (8KB); total 32KB
    __shared__ u8 smem[2][2 * BM * BK];

    const int tid = threadIdx.x;
    const int wave = tid >> 6;
    const int lane = tid & 63;
    const int fr = lane & 15;      // frag row (A) / col (B/D)
    const int quad = lane >> 4;    // 0..3

    const int bm = blockIdx.y * BM;
    const int bn = blockIdx.x * BN;

    const int wm = (wave >> 1) * 64;
    const int wn = (wave & 1) * 64;

    f32x4 acc[4][4] = {};

    // staging: each wave fills 2 chunks of 1024B per matrix per tile
    // lane i writes LDS [chunk*1024 + i*16] (LINEAR dest);
    // source row = 16*wave + i/4; source 16B-col = (i&3) ^ ((row>>1)&3)
    const int srow = 16 * wave + (lane >> 2);
    const int swzs = (lane >> 3) & 3;                 // == (srow>>1)&3 ; also for srow+64
    const int scol = ((lane & 3) ^ swzs) * 16;
    const u8* gA = A + (size_t)(bm + srow) * K + scol;
    const u8* gB = B + (size_t)(bn + srow) * K + scol;
    const int lofs = wave * 1024;                     // wave-uniform LDS base offset

    u8* As0 = smem[0];            u8* Bs0 = smem[0] + BM * BK;
    u8* As1 = smem[1];            u8* Bs1 = smem[1] + BM * BK;

    // read-side swizzle: row = wm + i*16 + fr, (row>>1)&3 == (fr>>1)&3 for all i,wm
    const int swzr = (fr >> 1) & 3;

    // prologue: stage tile 0 into buffer 0
    stage_tile(gA, gB, As0 + lofs, Bs0 + lofs, K);

    for (int k0 = 0; k0 < K; k0 += 2 * BK) {
        // ---- tile k0 in buf0 ----
        __syncthreads();                              // drains buf0's loads (implicit vmcnt(0))
        if (k0 + BK < K)
            stage_tile(gA + (k0 + BK), gB + (k0 + BK), As1 + lofs, Bs1 + lofs, K);
        compute_tile(As0, Bs0, acc, wm, wn, fr, quad, swzr);

        // ---- tile k0+BK in buf1 ----
        __syncthreads();                              // drains buf1's loads
        if (k0 + 2 * BK < K)
            stage_tile(gA + (k0 + 2 * BK), gB + (k0 + 2 * BK), As0 + lofs, Bs0 + lofs, K);
        compute_tile(As1, Bs1, acc, wm, wn, fr, quad, swzr);
    }

    // dequant epilogue: out = acc * (1/i_scale) * (1/w_scale) + bias
    const float mi = __uint_as_float(scales[0]);
    const float mw = __uint_as_float(scales[1]);
    const float i_scale = E4M3_AMAX / mi;
    const float w_scale = E4M3_AMAX / mw;
    const float deq = (1.0f / i_scale) * (1.0f / w_scale);

    #pragma unroll
    for (int i = 0; i < 4; ++i) {
        const int row0 = bm + wm + i * 16 + quad * 4;
        #pragma unroll
        for (int j = 0; j < 4; ++j) {
            const int col = bn + wn + j * 16 + fr;
            const float bv = bias[col];
            #pragma unroll
            for (int rg = 0; rg < 4; ++rg) {
                C[(size_t)(row0 + rg) * N + col] = acc[i][j][rg] * deq + bv;
            }
        }
    }
}

extern "C" void kernel_launch(void* const* d_in, const int* in_sizes, int n_in,
                              void* d_out, int out_size, void* d_ws, size_t ws_size,
                              hipStream_t stream) {
    const float* inp    = (const float*)d_in[0];
    const float* weight = (const float*)d_in[1];
    const float* bias   = (const float*)d_in[2];
    float* out = (float*)d_out;

    const int N = in_sizes[2];                        // 4096
    const int K = in_sizes[1] / N;                    // 4096
    const long icount = in_sizes[0];                  // 67108864
    const int M = (int)(icount / K);                  // 16384
    const long wcount = (long)N * K;

    u32* scales = (u32*)d_ws;
    u8* x8 = (u8*)d_ws + 256;
    u8* w8 = x8 + (size_t)M * K;

    // zero the amax accumulators (ws is poisoned 0xAA before each call)
    hipMemsetAsync(d_ws, 0, 16, stream);

    // fused abs-max: blocks [0,2048) -> inp, [2048,2560) -> weight
    maxabs2_kernel<<<2560, 256, 0, stream>>>(inp, icount / 4, scales + 0,
                                             weight, wcount / 4, scales + 1, 2048);
    // fused quantize: coalesced float4 load -> int store
    quant2_kernel<<<2560, 256, 0, stream>>>(inp, x8, icount / 4,
                                            weight, w8, wcount / 4, scales, 2048);

    dim3 grid(N / BN, M / BM);
    gemm_fp8_kernel<<<grid, 256, 0, stream>>>(x8, w8, bias, scales, out, M, N, K);
}